// Round 2
// baseline (74715.112 us; speedup 1.0000x reference)
//
#include <hip/hip_runtime.h>
#include <hip/hip_bf16.h>
#include <math.h>

namespace {

constexpr int D    = 768;
constexpr int NH   = 12;
constexpr int PTOT = 257;
constexpr int NB   = 2;
constexpr int TT   = 16;
constexpr int NTOK = NB * TT * PTOT;   // 8224
constexpr int NPAT = NB * TT * 256;    // 8192
constexpr int QKVD = 3 * D;            // 2304

// ---------------- unfold x -> xp (8192 x 768) ----------------
__global__ __launch_bounds__(256) void unfold_kernel(const float* __restrict__ x,
                                                     float* __restrict__ xp) {
  int idx = blockIdx.x * 256 + threadIdx.x;
  if (idx >= NPAT * D) return;
  int f  = idx % D;            // c*256 + i*16 + j
  int pg = idx / D;            // nt*256 + hp*16 + wp
  int c = f >> 8;
  int r = f & 255;
  int i = r >> 4, j = r & 15;
  int nt = pg >> 8;
  int s  = pg & 255;
  int hp = s >> 4, wp = s & 15;
  xp[idx] = x[(size_t)(nt * 3 + c) * 65536 + (size_t)(hp * 16 + i) * 256 + (wp * 16 + j)];
}

// ---------------- transpose patch_w (768x768) -> (feat, d) ----------------
__global__ __launch_bounds__(256) void transpose_pw(const float* __restrict__ pw,
                                                    float* __restrict__ pwT) {
  int idx = blockIdx.x * 256 + threadIdx.x;
  if (idx >= D * D) return;
  int d = idx / D, f = idx % D;
  pwT[(size_t)f * D + d] = pw[idx];
}

// ---------------- assemble h = [cls|tok] + pos + time (+patch_b) ----------------
__global__ __launch_bounds__(256) void assemble_kernel(const float* __restrict__ tok,
    const float* __restrict__ pb, const float* __restrict__ cls,
    const float* __restrict__ pos, const float* __restrict__ tim,
    float* __restrict__ h) {
  int idx = blockIdx.x * 256 + threadIdx.x;
  if (idx >= NTOK * D) return;
  int d = idx % D;
  int tokid = idx / D;
  int p  = tokid % PTOT;
  int nt = tokid / PTOT;
  int t  = nt % TT;
  float v = pos[p * D + d] + tim[t * D + d];
  if (p == 0) v += cls[d];
  else        v += tok[(size_t)(nt * 256 + (p - 1)) * D + d] + pb[d];
  h[idx] = v;
}

// ---------------- generic fp32 tiled GEMM: C = A(MxK)@B(KxN) + bias (+=) ----------------
__global__ __launch_bounds__(256) void gemm_nn(
    const float* __restrict__ A, const float* __restrict__ B,
    const float* __restrict__ bias, float* __restrict__ C,
    int M, int N, int K, int residual)
{
  __shared__ float As[16][64];
  __shared__ float Bs[16][64];
  int tid = threadIdx.x;
  int tx = tid & 15, ty = tid >> 4;
  int bm = blockIdx.y * 64, bn = blockIdx.x * 64;
  float acc[4][4] = {};
  for (int k0 = 0; k0 < K; k0 += 16) {
    int m  = tid >> 2;
    int kq = (tid & 3) << 2;
    float4 av = make_float4(0.f, 0.f, 0.f, 0.f);
    if (bm + m < M) av = *(const float4*)(A + (size_t)(bm + m) * K + k0 + kq);
    As[kq + 0][m] = av.x; As[kq + 1][m] = av.y; As[kq + 2][m] = av.z; As[kq + 3][m] = av.w;
    int kk = tid >> 4;
    int nn = (tid & 15) << 2;
    float4 bv = *(const float4*)(B + (size_t)(k0 + kk) * N + bn + nn);
    *(float4*)&Bs[kk][nn] = bv;
    __syncthreads();
    #pragma unroll
    for (int k = 0; k < 16; ++k) {
      float a[4], b[4];
      #pragma unroll
      for (int i = 0; i < 4; ++i) { a[i] = As[k][ty * 4 + i]; b[i] = Bs[k][tx * 4 + i]; }
      #pragma unroll
      for (int i = 0; i < 4; ++i)
        #pragma unroll
        for (int j = 0; j < 4; ++j)
          acc[i][j] = fmaf(a[i], b[j], acc[i][j]);
    }
    __syncthreads();
  }
  #pragma unroll
  for (int i = 0; i < 4; ++i) {
    int row = bm + ty * 4 + i;
    if (row >= M) continue;
    #pragma unroll
    for (int j = 0; j < 4; ++j) {
      int col = bn + tx * 4 + j;
      float v = acc[i][j];
      if (bias) v += bias[col];
      size_t off = (size_t)row * N + col;
      if (residual) C[off] += v; else C[off] = v;
    }
  }
}

// ---------------- spatial attention v2: tiled, LDS-staged, no shuffle hot loop ----
// block = 256 threads, grid = (384 frame-heads, 9 query-tiles of 32)
constexpr int QT = 32;    // queries per block
constexpr int SP = 261;   // score row pad (gcd(261%32=5,32)=1 -> conflict-free col reads)
constexpr int RP = 68;    // Q/KV row pad in floats (16B-aligned rows, breaks stride-64 banks)

__global__ __launch_bounds__(256) void attn_spatial2(const float* __restrict__ qkv,
                                                     float* __restrict__ o) {
  __shared__ float Qs[QT][RP];
  __shared__ float KV[64][RP];
  __shared__ float S[QT][SP];
  __shared__ float linv[QT];

  const int tid = threadIdx.x;
  const int bh = blockIdx.x;
  const int nt = bh / NH, head = bh % NH;
  const int q0 = blockIdx.y * QT;
  const size_t base = (size_t)nt * PTOT;
  const float* Kbase = qkv + D + head * 64;
  const float* Vbase = qkv + 2 * D + head * 64;

  // ---- load Q tile (pre-scaled by 1/8) ----
  {
    int r = tid >> 3;
    int c = (tid & 7) * 8;
    float4 v0 = make_float4(0.f, 0.f, 0.f, 0.f), v1 = v0;
    if (q0 + r < PTOT) {
      const float* qp = qkv + (base + q0 + r) * QKVD + head * 64 + c;
      v0 = *(const float4*)qp;
      v1 = *(const float4*)(qp + 4);
    }
    float4* dst = (float4*)&Qs[r][c];
    dst[0] = make_float4(v0.x * 0.125f, v0.y * 0.125f, v0.z * 0.125f, v0.w * 0.125f);
    dst[1] = make_float4(v1.x * 0.125f, v1.y * 0.125f, v1.z * 0.125f, v1.w * 0.125f);
  }

  // ---- phase 1: S = Q @ K^T (2 queries x 4 keys per thread) ----
  const int qa = tid & 15;           // queries qa and qa+16
  const int kb = (tid >> 4) * 4;     // keys kb..kb+3 within chunk
  for (int ck = 0; ck < 5; ++ck) {
    __syncthreads();                 // Q/prev-compute done before overwriting KV
    {
      int jr = tid >> 2;
      int cc = (tid & 3) * 16;
      int jg = ck * 64 + jr;
      float4 w0 = make_float4(0.f,0.f,0.f,0.f), w1 = w0, w2 = w0, w3 = w0;
      if (jg < PTOT) {
        const float* kp = Kbase + (base + jg) * QKVD + cc;
        w0 = ((const float4*)kp)[0]; w1 = ((const float4*)kp)[1];
        w2 = ((const float4*)kp)[2]; w3 = ((const float4*)kp)[3];
      }
      float4* dst = (float4*)&KV[jr][cc];
      dst[0] = w0; dst[1] = w1; dst[2] = w2; dst[3] = w3;
    }
    __syncthreads();
    float s0[4] = {}, s1[4] = {};
    #pragma unroll
    for (int d = 0; d < 64; d += 4) {
      float4 a0 = *(const float4*)&Qs[qa][d];
      float4 a1 = *(const float4*)&Qs[qa + 16][d];
      #pragma unroll
      for (int i = 0; i < 4; ++i) {
        float4 b = *(const float4*)&KV[kb + i][d];
        s0[i] += a0.x * b.x + a0.y * b.y + a0.z * b.z + a0.w * b.w;
        s1[i] += a1.x * b.x + a1.y * b.y + a1.z * b.z + a1.w * b.w;
      }
    }
    #pragma unroll
    for (int i = 0; i < 4; ++i) {
      int col = ck * 64 + kb + i;
      if (col < PTOT) { S[qa][col] = s0[i]; S[qa + 16][col] = s1[i]; }
    }
  }
  __syncthreads();

  // ---- softmax rows (8 lanes per row, width-8 xor reduce) ----
  {
    int r = tid >> 3;
    int seg = tid & 7;
    float m = -1e30f;
    for (int j = seg; j < PTOT; j += 8) m = fmaxf(m, S[r][j]);
    #pragma unroll
    for (int off = 1; off < 8; off <<= 1) m = fmaxf(m, __shfl_xor(m, off));
    float sum = 0.f;
    for (int j = seg; j < PTOT; j += 8) {
      float e = __expf(S[r][j] - m);
      S[r][j] = e;
      sum += e;
    }
    #pragma unroll
    for (int off = 1; off < 8; off <<= 1) sum += __shfl_xor(sum, off);
    if (seg == 0) linv[r] = 1.f / sum;
  }

  // ---- phase 2: O = P @ V (1 query x 8 dims per thread) ----
  const int q = tid & 31;
  const int dg = (tid >> 5) * 8;
  float4 oa = make_float4(0.f,0.f,0.f,0.f), ob = oa;
  for (int ck = 0; ck < 5; ++ck) {
    __syncthreads();
    {
      int jr = tid >> 2;
      int cc = (tid & 3) * 16;
      int jg = ck * 64 + jr;
      float4 w0 = make_float4(0.f,0.f,0.f,0.f), w1 = w0, w2 = w0, w3 = w0;
      if (jg < PTOT) {
        const float* vp = Vbase + (base + jg) * QKVD + cc;
        w0 = ((const float4*)vp)[0]; w1 = ((const float4*)vp)[1];
        w2 = ((const float4*)vp)[2]; w3 = ((const float4*)vp)[3];
      }
      float4* dst = (float4*)&KV[jr][cc];
      dst[0] = w0; dst[1] = w1; dst[2] = w2; dst[3] = w3;
    }
    __syncthreads();
    int jmax = min(64, PTOT - ck * 64);
    for (int j = 0; j < jmax; ++j) {
      float p = S[q][ck * 64 + j];
      float4 v0 = *(const float4*)&KV[j][dg];
      float4 v1 = *(const float4*)&KV[j][dg + 4];
      oa.x += p * v0.x; oa.y += p * v0.y; oa.z += p * v0.z; oa.w += p * v0.w;
      ob.x += p * v1.x; ob.y += p * v1.y; ob.z += p * v1.z; ob.w += p * v1.w;
    }
  }
  if (q0 + q < PTOT) {
    float inv = linv[q];
    float* op = o + (base + q0 + q) * D + head * 64 + dg;
    *(float4*)op       = make_float4(oa.x * inv, oa.y * inv, oa.z * inv, oa.w * inv);
    *(float4*)(op + 4) = make_float4(ob.x * inv, ob.y * inv, ob.z * inv, ob.w * inv);
  }
}

// ---------------- temporal attention: one wave per (n, head, p, query) ----------------
__global__ __launch_bounds__(256) void attn_temporal(const float* __restrict__ qkv,
                                                     float* __restrict__ o) {
  int lane = threadIdx.x & 63;
  int widx = threadIdx.x >> 6;
  int c  = blockIdx.x;                 // (n*NH + head)*PTOT + p, 0..6167
  int qi = blockIdx.y * 4 + widx;      // 0..15
  int p  = c % PTOT;
  int nh = c / PTOT;
  int n  = nh / NH, head = nh % NH;
  const float* qp = qkv + (size_t)((n * TT + qi) * PTOT + p) * QKVD + head * 64;
  float qd = qp[lane];
  float scr[TT];
  float mx = -1e30f;
  #pragma unroll
  for (int j = 0; j < TT; ++j) {
    const float* kp = qkv + (size_t)((n * TT + j) * PTOT + p) * QKVD + D + head * 64;
    float s = qd * kp[lane];
    #pragma unroll
    for (int off = 32; off; off >>= 1) s += __shfl_down(s, off);
    s = __shfl(s, 0) * 0.125f;
    scr[j] = s;
    mx = fmaxf(mx, s);
  }
  float sum = 0.f, acc = 0.f;
  #pragma unroll
  for (int j = 0; j < TT; ++j) {
    float e = __expf(scr[j] - mx);
    const float* vp = qkv + (size_t)((n * TT + j) * PTOT + p) * QKVD + 2 * D + head * 64;
    acc = fmaf(e, vp[lane], acc);
    sum += e;
  }
  o[(size_t)((n * TT + qi) * PTOT + p) * D + head * 64 + lane] = acc / sum;
}

// ---------------- final LN on cls rows + mean over t + head ----------------
__device__ __forceinline__ float block_sum(float v, float* lds) {
  #pragma unroll
  for (int off = 32; off; off >>= 1) v += __shfl_down(v, off);
  __syncthreads();
  if ((threadIdx.x & 63) == 0) lds[threadIdx.x >> 6] = v;
  __syncthreads();
  return lds[0] + lds[1] + lds[2] + lds[3];
}

__global__ __launch_bounds__(256) void head_kernel(const float* __restrict__ h,
    const float* __restrict__ g, const float* __restrict__ b,
    const float* __restrict__ hw, const float* __restrict__ hb,
    float* __restrict__ out) {
  __shared__ float lds[4];
  int n = blockIdx.x, tid = threadIdx.x;
  float logit = 0.f;
  for (int t = 0; t < TT; ++t) {
    const float* row = h + (size_t)((n * TT + t) * PTOT) * D;   // cls token (p=0)
    float v[3]; float s = 0.f;
    #pragma unroll
    for (int i = 0; i < 3; ++i) { v[i] = row[tid + 256 * i]; s += v[i]; }
    s = block_sum(s, lds);
    float mu = s * (1.f / D);
    float s2 = 0.f;
    #pragma unroll
    for (int i = 0; i < 3; ++i) { float d0 = v[i] - mu; s2 += d0 * d0; }
    s2 = block_sum(s2, lds);
    float rstd = rsqrtf(s2 * (1.f / D) + 1e-5f);
    float dot = 0.f;
    #pragma unroll
    for (int i = 0; i < 3; ++i) {
      int d0 = tid + 256 * i;
      float y = (v[i] - mu) * rstd * g[d0] + b[d0];
      dot += y * hw[d0];
    }
    dot = block_sum(dot, lds);
    logit += dot;
  }
  if (tid == 0) out[n] = logit * (1.f / TT) + hb[0];
}

} // namespace

extern "C" void kernel_launch(void* const* d_in, const int* in_sizes, int n_in,
                              void* d_out, int out_size, void* d_ws, size_t ws_size,
                              hipStream_t stream) {
  const float* x       = (const float*)d_in[0];
  const float* patch_w = (const float*)d_in[1];
  const float* patch_b = (const float*)d_in[2];
  const float* cls     = (const float*)d_in[3];
  const float* pos     = (const float*)d_in[4];
  const float* tim     = (const float*)d_in[5];
  const float* wqkv_s  = (const float*)d_in[6];
  const float* bqkv_s  = (const float*)d_in[7];
  const float* wqkv_t  = (const float*)d_in[8];
  const float* bqkv_t  = (const float*)d_in[9];
  const float* wproj   = (const float*)d_in[10];
  const float* bproj   = (const float*)d_in[11];
  const float* ln_g    = (const float*)d_in[12];
  const float* ln_b    = (const float*)d_in[13];
  const float* head_w  = (const float*)d_in[14];
  const float* head_b  = (const float*)d_in[15];
  float* out = (float*)d_out;

  // workspace layout (fp32): h | qkv | o   (xp & pwT alias qkv pre-layers; tok aliases o)
  float* h   = (float*)d_ws;
  float* qkv = h   + (size_t)NTOK * D;
  float* o   = qkv + (size_t)NTOK * QKVD;
  float* xp  = qkv;
  float* pwT = qkv + (size_t)NPAT * D;
  float* tok = o;

  // ---- patch embed ----
  unfold_kernel<<<(NPAT * D + 255) / 256, 256, 0, stream>>>(x, xp);
  transpose_pw<<<(D * D + 255) / 256, 256, 0, stream>>>(patch_w, pwT);
  gemm_nn<<<dim3(D / 64, (NPAT + 63) / 64), 256, 0, stream>>>(
      xp, pwT, nullptr, tok, NPAT, D, D, 0);
  assemble_kernel<<<(NTOK * D + 255) / 256, 256, 0, stream>>>(tok, patch_b, cls, pos, tim, h);

  // ---- transformer layers ----
  for (int l = 0; l < 12; ++l) {
    gemm_nn<<<dim3(QKVD / 64, (NTOK + 63) / 64), 256, 0, stream>>>(
        h, wqkv_s + (size_t)l * D * QKVD, bqkv_s + (size_t)l * QKVD, qkv, NTOK, QKVD, D, 0);
    attn_spatial2<<<dim3(NB * TT * NH, (PTOT + QT - 1) / QT), 256, 0, stream>>>(qkv, o);
    gemm_nn<<<dim3(D / 64, (NTOK + 63) / 64), 256, 0, stream>>>(
        o, wproj + (size_t)l * D * D, bproj + (size_t)l * D, h, NTOK, D, D, 1);

    gemm_nn<<<dim3(QKVD / 64, (NTOK + 63) / 64), 256, 0, stream>>>(
        h, wqkv_t + (size_t)l * D * QKVD, bqkv_t + (size_t)l * QKVD, qkv, NTOK, QKVD, D, 0);
    attn_temporal<<<dim3(NB * NH * PTOT, 4), 256, 0, stream>>>(qkv, o);
    gemm_nn<<<dim3(D / 64, (NTOK + 63) / 64), 256, 0, stream>>>(
        o, wproj + (size_t)l * D * D, bproj + (size_t)l * D, h, NTOK, D, D, 1);
  }

  // ---- final LN (cls rows only) + temporal mean + head ----
  head_kernel<<<2, 256, 0, stream>>>(h, ln_g, ln_b, head_w, head_b, out);
}

// Round 3
// 5564.969 us; speedup vs baseline: 13.4260x; 13.4260x over previous
//
#include <hip/hip_runtime.h>
#include <hip/hip_bf16.h>
#include <math.h>

namespace {

constexpr int D    = 768;
constexpr int NH   = 12;
constexpr int PTOT = 257;
constexpr int NB   = 2;
constexpr int TT   = 16;
constexpr int NTOK = NB * TT * PTOT;   // 8224
constexpr int NPAT = NB * TT * 256;    // 8192
constexpr int QKVD = 3 * D;            // 2304

typedef short short8  __attribute__((ext_vector_type(8)));
typedef float float4v __attribute__((ext_vector_type(4)));

__device__ __forceinline__ float bf2f(unsigned short u) {
  unsigned v = ((unsigned)u) << 16;
  float f; __builtin_memcpy(&f, &v, 4); return f;
}
__device__ __forceinline__ unsigned short f2bf(float f) {
  unsigned u; __builtin_memcpy(&u, &f, 4);
  u += 0x7FFFu + ((u >> 16) & 1u);   // RNE
  return (unsigned short)(u >> 16);
}

// ---------------- unfold x -> xp (8192 x 768) fp32 ----------------
__global__ __launch_bounds__(256) void unfold_kernel(const float* __restrict__ x,
                                                     float* __restrict__ xp) {
  int idx = blockIdx.x * 256 + threadIdx.x;
  if (idx >= NPAT * D) return;
  int f  = idx % D;
  int pg = idx / D;
  int c = f >> 8;
  int r = f & 255;
  int i = r >> 4, j = r & 15;
  int nt = pg >> 8;
  int s  = pg & 255;
  int hp = s >> 4, wp = s & 15;
  xp[idx] = x[(size_t)(nt * 3 + c) * 65536 + (size_t)(hp * 16 + i) * 256 + (wp * 16 + j)];
}

// ---------------- transpose patch_w (768x768) fp32 ----------------
__global__ __launch_bounds__(256) void transpose_pw(const float* __restrict__ pw,
                                                    float* __restrict__ pwT) {
  int idx = blockIdx.x * 256 + threadIdx.x;
  if (idx >= D * D) return;
  int d = idx / D, f = idx % D;
  pwT[(size_t)f * D + d] = pw[idx];
}

// ---------------- weight transpose + fp32->bf16: W[L][768][N] -> WT[L][N][768] ----
__global__ __launch_bounds__(256) void wconv(const float* __restrict__ W,
                                             unsigned short* __restrict__ WT, int N) {
  __shared__ float tile[32][33];
  int l = blockIdx.z;
  const float* w = W + (size_t)l * 768 * N;
  unsigned short* wt = WT + (size_t)l * 768 * N;
  int n0 = blockIdx.x * 32, k0 = blockIdx.y * 32;
  int t = threadIdx.x;
  {
    int r = t >> 3, c4 = (t & 7) * 4;
    float4 v = *(const float4*)(w + (size_t)(k0 + r) * N + n0 + c4);
    tile[r][c4 + 0] = v.x; tile[r][c4 + 1] = v.y;
    tile[r][c4 + 2] = v.z; tile[r][c4 + 3] = v.w;
  }
  __syncthreads();
  {
    int rn = t >> 3, ck = (t & 7) * 4;
    ushort4 o;
    o.x = f2bf(tile[ck + 0][rn]); o.y = f2bf(tile[ck + 1][rn]);
    o.z = f2bf(tile[ck + 2][rn]); o.w = f2bf(tile[ck + 3][rn]);
    *(ushort4*)(wt + (size_t)(n0 + rn) * 768 + k0 + ck) = o;
  }
}

// ---------------- assemble h (fp32) + hb (bf16 mirror) ----------------
__global__ __launch_bounds__(256) void assemble_kernel(const float* __restrict__ tok,
    const float* __restrict__ pb, const float* __restrict__ cls,
    const float* __restrict__ pos, const float* __restrict__ tim,
    float* __restrict__ h, unsigned short* __restrict__ hb) {
  int idx = blockIdx.x * 256 + threadIdx.x;
  if (idx >= NTOK * D) return;
  int d = idx % D;
  int tokid = idx / D;
  int p  = tokid % PTOT;
  int nt = tokid / PTOT;
  int t  = nt % TT;
  float v = pos[p * D + d] + tim[t * D + d];
  if (p == 0) v += cls[d];
  else        v += tok[(size_t)(nt * 256 + (p - 1)) * D + d] + pb[d];
  h[idx] = v;
  hb[idx] = f2bf(v);
}

// ---------------- fp32 tiled GEMM (patch embed only) ----------------
__global__ __launch_bounds__(256) void gemm_nn(
    const float* __restrict__ A, const float* __restrict__ B,
    const float* __restrict__ bias, float* __restrict__ C,
    int M, int N, int K, int residual)
{
  __shared__ float As[16][64];
  __shared__ float Bs[16][64];
  int tid = threadIdx.x;
  int tx = tid & 15, ty = tid >> 4;
  int bm = blockIdx.y * 64, bn = blockIdx.x * 64;
  float acc[4][4] = {};
  for (int k0 = 0; k0 < K; k0 += 16) {
    int m  = tid >> 2;
    int kq = (tid & 3) << 2;
    float4 av = make_float4(0.f, 0.f, 0.f, 0.f);
    if (bm + m < M) av = *(const float4*)(A + (size_t)(bm + m) * K + k0 + kq);
    As[kq + 0][m] = av.x; As[kq + 1][m] = av.y; As[kq + 2][m] = av.z; As[kq + 3][m] = av.w;
    int kk = tid >> 4;
    int nn = (tid & 15) << 2;
    float4 bv = *(const float4*)(B + (size_t)(k0 + kk) * N + bn + nn);
    *(float4*)&Bs[kk][nn] = bv;
    __syncthreads();
    #pragma unroll
    for (int k = 0; k < 16; ++k) {
      float a[4], b[4];
      #pragma unroll
      for (int i = 0; i < 4; ++i) { a[i] = As[k][ty * 4 + i]; b[i] = Bs[k][tx * 4 + i]; }
      #pragma unroll
      for (int i = 0; i < 4; ++i)
        #pragma unroll
        for (int j = 0; j < 4; ++j)
          acc[i][j] = fmaf(a[i], b[j], acc[i][j]);
    }
    __syncthreads();
  }
  #pragma unroll
  for (int i = 0; i < 4; ++i) {
    int row = bm + ty * 4 + i;
    if (row >= M) continue;
    #pragma unroll
    for (int j = 0; j < 4; ++j) {
      int col = bn + tx * 4 + j;
      float v = acc[i][j];
      if (bias) v += bias[col];
      size_t off = (size_t)row * N + col;
      if (residual) C[off] += v; else C[off] = v;
    }
  }
}

// ---------------- bf16 MFMA GEMM: C = A(MxK) @ BT(NxK)^T + bias ----------------
// mode 0: Cb (bf16) = result.  mode 1: Hf += result (fp32); Hb = bf16(new Hf).
// 128x128 tile, BK=32, 4 waves each 64x64. K = 768.
__global__ __launch_bounds__(256) void gemm_bf16(
    const unsigned short* __restrict__ A,
    const unsigned short* __restrict__ BT,
    const float* __restrict__ bias,
    unsigned short* __restrict__ Cb,
    float* __restrict__ Hf,
    unsigned short* __restrict__ Hb,
    int M, int N, int mode)
{
  constexpr int K = 768;
  __shared__ unsigned short As[128][40];   // padded: 80B rows -> 2-way-free frag reads
  __shared__ unsigned short Bs[128][40];
  int tid = threadIdx.x;
  int m0 = blockIdx.y * 128, n0 = blockIdx.x * 128;
  int w = tid >> 6, lane = tid & 63;
  int quad = lane >> 4, l16 = lane & 15;
  int wm = (w & 1) * 64, wn = (w >> 1) * 64;
  float4v acc[4][4] = {};

  for (int k0 = 0; k0 < K; k0 += 32) {
    __syncthreads();
    #pragma unroll
    for (int e = 0; e < 2; ++e) {
      int chunk = e * 256 + tid;           // 512 chunks of 16B
      int row = chunk >> 2, qo = (chunk & 3) * 8;
      int ar = min(m0 + row, M - 1);
      *(uint4*)&As[row][qo] = *(const uint4*)(A  + (size_t)ar * K + k0 + qo);
      *(uint4*)&Bs[row][qo] = *(const uint4*)(BT + (size_t)(n0 + row) * K + k0 + qo);
    }
    __syncthreads();
    short8 af[4], bfr[4];
    #pragma unroll
    for (int i = 0; i < 4; ++i) {
      af[i]  = *(const short8*)&As[wm + i * 16 + l16][quad * 8];
      bfr[i] = *(const short8*)&Bs[wn + i * 16 + l16][quad * 8];
    }
    #pragma unroll
    for (int i = 0; i < 4; ++i)
      #pragma unroll
      for (int j = 0; j < 4; ++j)
        acc[i][j] = __builtin_amdgcn_mfma_f32_16x16x32_bf16(af[i], bfr[j], acc[i][j], 0, 0, 0);
  }

  #pragma unroll
  for (int j = 0; j < 4; ++j) {
    int col = n0 + wn + j * 16 + l16;
    float bv = bias[col];
    #pragma unroll
    for (int i = 0; i < 4; ++i) {
      #pragma unroll
      for (int r = 0; r < 4; ++r) {
        int row = m0 + wm + i * 16 + quad * 4 + r;
        if (row < M) {
          float v = acc[i][j][r] + bv;
          size_t off = (size_t)row * N + col;
          if (mode == 0) {
            Cb[off] = f2bf(v);
          } else {
            float nv = Hf[off] + v;
            Hf[off] = nv;
            Hb[off] = f2bf(nv);
          }
        }
      }
    }
  }
}

// ---------------- spatial attention (bf16 MFMA, flash-tiled) ----------------
// grid = 384 (nt*NH+head), block = 256 (4 waves). LDS = 56.3 KB -> 2 blocks/CU.
__global__ __launch_bounds__(256, 2) void attn_spatial3(
    const unsigned short* __restrict__ qkv,  // [NTOK][2304] bf16
    unsigned short* __restrict__ o)          // [NTOK][768]  bf16
{
  __shared__ unsigned short Qs[64][72];      // 144B rows: frag reads 2-way free
  __shared__ unsigned short KVs[64][72];
  __shared__ unsigned short Ps[4][16][296];  // 592B rows
  int tid = threadIdx.x;
  int w = tid >> 6, lane = tid & 63;
  int quad = lane >> 4, l16 = lane & 15;
  int bh = blockIdx.x, nt = bh / NH, head = bh % NH;
  size_t base = (size_t)nt * PTOT;
  const unsigned short* Qg = qkv + head * 64;
  const unsigned short* Kg = qkv + 768 + head * 64;
  const unsigned short* Vg = qkv + 1536 + head * 64;

  for (int q0 = 0; q0 < 320; q0 += 64) {
    __syncthreads();   // protect Qs/Ps from previous iteration readers
    // ---- stage Q (pre-scaled by 1/8, exact in bf16) ----
    #pragma unroll
    for (int e = 0; e < 2; ++e) {
      int chunk = e * 256 + tid;            // 512 chunks of 16B (64 rows x 8)
      int row = chunk >> 3, off = (chunk & 7) * 8;
      int qr = min(q0 + row, PTOT - 1);
      uint4 u = *(const uint4*)(Qg + (base + qr) * (size_t)QKVD + off);
      const unsigned short* pu = (const unsigned short*)&u;
      unsigned short s[8];
      #pragma unroll
      for (int i = 0; i < 8; ++i) {
        float f = bf2f(pu[i]) * 0.125f;
        unsigned ub; __builtin_memcpy(&ub, &f, 4);
        s[i] = (unsigned short)(ub >> 16);  // exact (pow2 scale)
      }
      *(uint4*)&Qs[row][off] = *(const uint4*)s;
    }
    __syncthreads();
    int qrow = w * 16 + l16;
    short8 qa0 = *(const short8*)&Qs[qrow][quad * 8];
    short8 qa1 = *(const short8*)&Qs[qrow][32 + quad * 8];

    // ---- scores: S strip 16 x 272 per wave, in registers ----
    float4v st[17];
    #pragma unroll
    for (int kc = 0; kc < 5; ++kc) {
      __syncthreads();
      #pragma unroll
      for (int e = 0; e < 2; ++e) {
        int chunk = e * 256 + tid;
        int row = chunk >> 3, off = (chunk & 7) * 8;
        int kr = min(kc * 64 + row, PTOT - 1);
        *(uint4*)&KVs[row][off] = *(const uint4*)(Kg + (base + kr) * (size_t)QKVD + off);
      }
      __syncthreads();
      #pragma unroll
      for (int tt = 0; tt < 4; ++tt) {
        int t = kc * 4 + tt;
        if (t < 17) {
          short8 kb0 = *(const short8*)&KVs[tt * 16 + l16][quad * 8];
          short8 kb1 = *(const short8*)&KVs[tt * 16 + l16][32 + quad * 8];
          float4v a = {0.f, 0.f, 0.f, 0.f};
          a = __builtin_amdgcn_mfma_f32_16x16x32_bf16(qa0, kb0, a, 0, 0, 0);
          a = __builtin_amdgcn_mfma_f32_16x16x32_bf16(qa1, kb1, a, 0, 0, 0);
          st[t] = a;
        }
      }
    }
    // mask invalid keys in last tile (cols 257..271)
    if (l16 >= 1) {
      st[16][0] = -1e30f; st[16][1] = -1e30f; st[16][2] = -1e30f; st[16][3] = -1e30f;
    }
    // ---- softmax over rows (16 lanes of the quad hold the row) ----
    float mx[4] = {-1e30f, -1e30f, -1e30f, -1e30f};
    #pragma unroll
    for (int t = 0; t < 17; ++t)
      #pragma unroll
      for (int r = 0; r < 4; ++r) mx[r] = fmaxf(mx[r], st[t][r]);
    #pragma unroll
    for (int off = 1; off < 16; off <<= 1)
      #pragma unroll
      for (int r = 0; r < 4; ++r) mx[r] = fmaxf(mx[r], __shfl_xor(mx[r], off));
    float sm[4] = {0.f, 0.f, 0.f, 0.f};
    #pragma unroll
    for (int t = 0; t < 17; ++t)
      #pragma unroll
      for (int r = 0; r < 4; ++r) {
        float e = __expf(st[t][r] - mx[r]);
        st[t][r] = e;
        sm[r] += e;
      }
    #pragma unroll
    for (int off = 1; off < 16; off <<= 1)
      #pragma unroll
      for (int r = 0; r < 4; ++r) sm[r] += __shfl_xor(sm[r], off);
    float linv[4];
    #pragma unroll
    for (int r = 0; r < 4; ++r) linv[r] = 1.f / sm[r];

    // ---- write P (unnormalized) to LDS; zero-pad cols 272..287 ----
    #pragma unroll
    for (int t = 0; t < 17; ++t)
      #pragma unroll
      for (int r = 0; r < 4; ++r)
        Ps[w][quad * 4 + r][t * 16 + l16] = f2bf(st[t][r]);
    {
      ushort4 z = {0, 0, 0, 0};
      *(ushort4*)&Ps[w][lane >> 2][272 + (lane & 3) * 4] = z;
    }

    // ---- PV: O strip 16 x 64 per wave ----
    float4v oacc[4] = {};
    #pragma unroll
    for (int vc = 0; vc < 5; ++vc) {
      __syncthreads();
      #pragma unroll
      for (int e = 0; e < 2; ++e) {
        int chunk = e * 256 + tid;
        int row = chunk >> 3, off = (chunk & 7) * 8;
        int vr = min(vc * 64 + row, PTOT - 1);
        *(uint4*)&KVs[row][off] = *(const uint4*)(Vg + (base + vr) * (size_t)QKVD + off);
      }
      __syncthreads();
      int ksmax = (vc == 4) ? 1 : 2;
      for (int ks = 0; ks < ksmax; ++ks) {
        int kglob = vc * 64 + ks * 32;
        short8 pa = *(const short8*)&Ps[w][l16][kglob + quad * 8];
        #pragma unroll
        for (int j = 0; j < 4; ++j) {
          unsigned short vb[8];
          #pragma unroll
          for (int jj = 0; jj < 8; ++jj)
            vb[jj] = KVs[ks * 32 + quad * 8 + jj][j * 16 + l16];
          oacc[j] = __builtin_amdgcn_mfma_f32_16x16x32_bf16(pa, *(const short8*)vb, oacc[j], 0, 0, 0);
        }
      }
    }
    // ---- store O ----
    #pragma unroll
    for (int r = 0; r < 4; ++r) {
      int qg = q0 + w * 16 + quad * 4 + r;
      if (qg < PTOT) {
        #pragma unroll
        for (int j = 0; j < 4; ++j)
          o[(base + qg) * (size_t)D + head * 64 + j * 16 + l16] = f2bf(oacc[j][r] * linv[r]);
      }
    }
  }
}

// ---------------- temporal attention (bf16 in/out, wave per query) ----------------
__global__ __launch_bounds__(256) void attn_temporal(const unsigned short* __restrict__ qkv,
                                                     unsigned short* __restrict__ o) {
  int lane = threadIdx.x & 63;
  int widx = threadIdx.x >> 6;
  int c  = blockIdx.x;                 // (n*NH + head)*PTOT + p
  int qi = blockIdx.y * 4 + widx;
  int p  = c % PTOT;
  int nh = c / PTOT;
  int n  = nh / NH, head = nh % NH;
  const unsigned short* qp = qkv + (size_t)((n * TT + qi) * PTOT + p) * QKVD + head * 64;
  float qd = bf2f(qp[lane]);
  float scr[TT];
  float mxv = -1e30f;
  #pragma unroll
  for (int j = 0; j < TT; ++j) {
    const unsigned short* kp = qkv + (size_t)((n * TT + j) * PTOT + p) * QKVD + 768 + head * 64;
    float s = qd * bf2f(kp[lane]);
    #pragma unroll
    for (int off = 32; off; off >>= 1) s += __shfl_down(s, off);
    s = __shfl(s, 0) * 0.125f;
    scr[j] = s;
    mxv = fmaxf(mxv, s);
  }
  float sum = 0.f, acc = 0.f;
  #pragma unroll
  for (int j = 0; j < TT; ++j) {
    float e = __expf(scr[j] - mxv);
    const unsigned short* vp = qkv + (size_t)((n * TT + j) * PTOT + p) * QKVD + 1536 + head * 64;
    acc = fmaf(e, bf2f(vp[lane]), acc);
    sum += e;
  }
  o[(size_t)((n * TT + qi) * PTOT + p) * D + head * 64 + lane] = f2bf(acc / sum);
}

// ---------------- final LN on cls rows + mean over t + head ----------------
__device__ __forceinline__ float block_sum(float v, float* lds) {
  #pragma unroll
  for (int off = 32; off; off >>= 1) v += __shfl_down(v, off);
  __syncthreads();
  if ((threadIdx.x & 63) == 0) lds[threadIdx.x >> 6] = v;
  __syncthreads();
  return lds[0] + lds[1] + lds[2] + lds[3];
}

__global__ __launch_bounds__(256) void head_kernel(const float* __restrict__ h,
    const float* __restrict__ g, const float* __restrict__ b,
    const float* __restrict__ hw, const float* __restrict__ hb,
    float* __restrict__ out) {
  __shared__ float lds[4];
  int n = blockIdx.x, tid = threadIdx.x;
  float logit = 0.f;
  for (int t = 0; t < TT; ++t) {
    const float* row = h + (size_t)((n * TT + t) * PTOT) * D;
    float v[3]; float s = 0.f;
    #pragma unroll
    for (int i = 0; i < 3; ++i) { v[i] = row[tid + 256 * i]; s += v[i]; }
    s = block_sum(s, lds);
    float mu = s * (1.f / D);
    float s2 = 0.f;
    #pragma unroll
    for (int i = 0; i < 3; ++i) { float d0 = v[i] - mu; s2 += d0 * d0; }
    s2 = block_sum(s2, lds);
    float rstd = rsqrtf(s2 * (1.f / D) + 1e-5f);
    float dot = 0.f;
    #pragma unroll
    for (int i = 0; i < 3; ++i) {
      int d0 = tid + 256 * i;
      float y = (v[i] - mu) * rstd * g[d0] + b[d0];
      dot += y * hw[d0];
    }
    dot = block_sum(dot, lds);
    logit += dot;
  }
  if (tid == 0) out[n] = logit * (1.f / TT) + hb[0];
}

} // namespace

extern "C" void kernel_launch(void* const* d_in, const int* in_sizes, int n_in,
                              void* d_out, int out_size, void* d_ws, size_t ws_size,
                              hipStream_t stream) {
  const float* x       = (const float*)d_in[0];
  const float* patch_w = (const float*)d_in[1];
  const float* patch_b = (const float*)d_in[2];
  const float* cls     = (const float*)d_in[3];
  const float* pos     = (const float*)d_in[4];
  const float* tim     = (const float*)d_in[5];
  const float* wqkv_s  = (const float*)d_in[6];
  const float* bqkv_s  = (const float*)d_in[7];
  const float* wqkv_t  = (const float*)d_in[8];
  const float* bqkv_t  = (const float*)d_in[9];
  const float* wproj   = (const float*)d_in[10];
  const float* bproj   = (const float*)d_in[11];
  const float* ln_g    = (const float*)d_in[12];
  const float* ln_b    = (const float*)d_in[13];
  const float* head_w  = (const float*)d_in[14];
  const float* head_b  = (const float*)d_in[15];
  float* out = (float*)d_out;

  // ---- workspace layout ----
  char* p = (char*)d_ws;
  float* h = (float*)p;                 p += (size_t)NTOK * D * 4;      // 25.3 MB fp32 residual
  unsigned short* hb = (unsigned short*)p;   p += (size_t)NTOK * D * 2; // bf16 mirror
  unsigned short* qkvb = (unsigned short*)p; p += (size_t)NTOK * QKVD * 2;
  unsigned short* ob = (unsigned short*)p;   p += (size_t)NTOK * D * 2;
  unsigned short* wsT = (unsigned short*)p;  p += (size_t)12 * QKVD * D * 2;
  unsigned short* wtT = (unsigned short*)p;  p += (size_t)12 * QKVD * D * 2;
  unsigned short* wpT = (unsigned short*)p;  p += (size_t)12 * D * D * 2;
  // pre-layer fp32 scratch aliases regions used only later:
  float* xp  = (float*)qkvb;       // 25.2 MB <= 37.9 MB
  float* pwT = (float*)ob;         //  2.4 MB <= 12.6 MB
  float* tok = (float*)wsT;        // 25.2 MB <= 42.5 MB (wconv runs after assemble)

  // ---- patch embed (fp32 for accuracy: its error persists in the residual) ----
  unfold_kernel<<<(NPAT * D + 255) / 256, 256, 0, stream>>>(x, xp);
  transpose_pw<<<(D * D + 255) / 256, 256, 0, stream>>>(patch_w, pwT);
  gemm_nn<<<dim3(D / 64, NPAT / 64), 256, 0, stream>>>(xp, pwT, nullptr, tok, NPAT, D, D, 0);
  assemble_kernel<<<(NTOK * D + 255) / 256, 256, 0, stream>>>(tok, patch_b, cls, pos, tim, h, hb);

  // ---- weights -> transposed bf16 (every call; overwrites tok alias afterwards) ----
  wconv<<<dim3(QKVD / 32, D / 32, 12), 256, 0, stream>>>(wqkv_s, wsT, QKVD);
  wconv<<<dim3(QKVD / 32, D / 32, 12), 256, 0, stream>>>(wqkv_t, wtT, QKVD);
  wconv<<<dim3(D / 32, D / 32, 12), 256, 0, stream>>>(wproj, wpT, D);

  // ---- transformer layers ----
  const int MB = (NTOK + 127) / 128;   // 65
  for (int l = 0; l < 12; ++l) {
    gemm_bf16<<<dim3(QKVD / 128, MB), 256, 0, stream>>>(
        hb, wsT + (size_t)l * QKVD * D, bqkv_s + (size_t)l * QKVD,
        qkvb, nullptr, nullptr, NTOK, QKVD, 0);
    attn_spatial3<<<NB * TT * NH, 256, 0, stream>>>(qkvb, ob);
    gemm_bf16<<<dim3(D / 128, MB), 256, 0, stream>>>(
        ob, wpT + (size_t)l * D * D, bproj + (size_t)l * D,
        nullptr, h, hb, NTOK, D, 1);

    gemm_bf16<<<dim3(QKVD / 128, MB), 256, 0, stream>>>(
        hb, wtT + (size_t)l * QKVD * D, bqkv_t + (size_t)l * QKVD,
        qkvb, nullptr, nullptr, NTOK, QKVD, 0);
    attn_temporal<<<dim3(NB * NH * PTOT, 4), 256, 0, stream>>>(qkvb, ob);
    gemm_bf16<<<dim3(D / 128, MB), 256, 0, stream>>>(
        ob, wpT + (size_t)l * D * D, bproj + (size_t)l * D,
        nullptr, h, hb, NTOK, D, 1);
  }

  // ---- final LN (cls rows only) + temporal mean + head ----
  head_kernel<<<2, 256, 0, stream>>>(h, ln_g, ln_b, head_w, head_b, out);
}

// Round 4
// 4230.302 us; speedup vs baseline: 17.6619x; 1.3155x over previous
//
#include <hip/hip_runtime.h>
#include <hip/hip_bf16.h>
#include <math.h>

namespace {

constexpr int D    = 768;
constexpr int NH   = 12;
constexpr int PTOT = 257;
constexpr int NB   = 2;
constexpr int TT   = 16;
constexpr int NTOK = NB * TT * PTOT;   // 8224
constexpr int NPAT = NB * TT * 256;    // 8192
constexpr int QKVD = 3 * D;            // 2304

typedef short short8  __attribute__((ext_vector_type(8)));
typedef float float4v __attribute__((ext_vector_type(4)));

__device__ __forceinline__ float bf2f(unsigned short u) {
  unsigned v = ((unsigned)u) << 16;
  float f; __builtin_memcpy(&f, &v, 4); return f;
}
__device__ __forceinline__ unsigned short f2bf(float f) {
  unsigned u; __builtin_memcpy(&u, &f, 4);
  u += 0x7FFFu + ((u >> 16) & 1u);   // RNE
  return (unsigned short)(u >> 16);
}

// async global->LDS, 16B per lane, dst = uniform base + lane*16
__device__ __forceinline__ void gload_lds16(const void* g, void* l) {
  __builtin_amdgcn_global_load_lds((const __attribute__((address_space(1))) void*)g,
                                   (__attribute__((address_space(3))) void*)l, 16, 0, 0);
}

// ---------------- unfold x -> xp (8192 x 768) fp32 ----------------
__global__ __launch_bounds__(256) void unfold_kernel(const float* __restrict__ x,
                                                     float* __restrict__ xp) {
  int idx = blockIdx.x * 256 + threadIdx.x;
  if (idx >= NPAT * D) return;
  int f  = idx % D;
  int pg = idx / D;
  int c = f >> 8;
  int r = f & 255;
  int i = r >> 4, j = r & 15;
  int nt = pg >> 8;
  int s  = pg & 255;
  int hp = s >> 4, wp = s & 15;
  xp[idx] = x[(size_t)(nt * 3 + c) * 65536 + (size_t)(hp * 16 + i) * 256 + (wp * 16 + j)];
}

// ---------------- transpose patch_w (768x768) fp32 ----------------
__global__ __launch_bounds__(256) void transpose_pw(const float* __restrict__ pw,
                                                    float* __restrict__ pwT) {
  int idx = blockIdx.x * 256 + threadIdx.x;
  if (idx >= D * D) return;
  int d = idx / D, f = idx % D;
  pwT[(size_t)f * D + d] = pw[idx];
}

// ---------------- weight transpose + fp32->bf16: W[L][768][N] -> WT[L][N][768] ----
__global__ __launch_bounds__(256) void wconv(const float* __restrict__ W,
                                             unsigned short* __restrict__ WT, int N) {
  __shared__ float tile[32][33];
  int l = blockIdx.z;
  const float* w = W + (size_t)l * 768 * N;
  unsigned short* wt = WT + (size_t)l * 768 * N;
  int n0 = blockIdx.x * 32, k0 = blockIdx.y * 32;
  int t = threadIdx.x;
  {
    int r = t >> 3, c4 = (t & 7) * 4;
    float4 v = *(const float4*)(w + (size_t)(k0 + r) * N + n0 + c4);
    tile[r][c4 + 0] = v.x; tile[r][c4 + 1] = v.y;
    tile[r][c4 + 2] = v.z; tile[r][c4 + 3] = v.w;
  }
  __syncthreads();
  {
    int rn = t >> 3, ck = (t & 7) * 4;
    ushort4 o;
    o.x = f2bf(tile[ck + 0][rn]); o.y = f2bf(tile[ck + 1][rn]);
    o.z = f2bf(tile[ck + 2][rn]); o.w = f2bf(tile[ck + 3][rn]);
    *(ushort4*)(wt + (size_t)(n0 + rn) * 768 + k0 + ck) = o;
  }
}

// ---------------- assemble h (fp32) + hb (bf16 mirror) ----------------
__global__ __launch_bounds__(256) void assemble_kernel(const float* __restrict__ tok,
    const float* __restrict__ pb, const float* __restrict__ cls,
    const float* __restrict__ pos, const float* __restrict__ tim,
    float* __restrict__ h, unsigned short* __restrict__ hb) {
  int idx = blockIdx.x * 256 + threadIdx.x;
  if (idx >= NTOK * D) return;
  int d = idx % D;
  int tokid = idx / D;
  int p  = tokid % PTOT;
  int nt = tokid / PTOT;
  int t  = nt % TT;
  float v = pos[p * D + d] + tim[t * D + d];
  if (p == 0) v += cls[d];
  else        v += tok[(size_t)(nt * 256 + (p - 1)) * D + d] + pb[d];
  h[idx] = v;
  hb[idx] = f2bf(v);
}

// ---------------- fp32 tiled GEMM (patch embed only) ----------------
__global__ __launch_bounds__(256) void gemm_nn(
    const float* __restrict__ A, const float* __restrict__ B,
    const float* __restrict__ bias, float* __restrict__ C,
    int M, int N, int K, int residual)
{
  __shared__ float As[16][64];
  __shared__ float Bs[16][64];
  int tid = threadIdx.x;
  int tx = tid & 15, ty = tid >> 4;
  int bm = blockIdx.y * 64, bn = blockIdx.x * 64;
  float acc[4][4] = {};
  for (int k0 = 0; k0 < K; k0 += 16) {
    int m  = tid >> 2;
    int kq = (tid & 3) << 2;
    float4 av = make_float4(0.f, 0.f, 0.f, 0.f);
    if (bm + m < M) av = *(const float4*)(A + (size_t)(bm + m) * K + k0 + kq);
    As[kq + 0][m] = av.x; As[kq + 1][m] = av.y; As[kq + 2][m] = av.z; As[kq + 3][m] = av.w;
    int kk = tid >> 4;
    int nn = (tid & 15) << 2;
    float4 bv = *(const float4*)(B + (size_t)(k0 + kk) * N + bn + nn);
    *(float4*)&Bs[kk][nn] = bv;
    __syncthreads();
    #pragma unroll
    for (int k = 0; k < 16; ++k) {
      float a[4], b[4];
      #pragma unroll
      for (int i = 0; i < 4; ++i) { a[i] = As[k][ty * 4 + i]; b[i] = Bs[k][tx * 4 + i]; }
      #pragma unroll
      for (int i = 0; i < 4; ++i)
        #pragma unroll
        for (int j = 0; j < 4; ++j)
          acc[i][j] = fmaf(a[i], b[j], acc[i][j]);
    }
    __syncthreads();
  }
  #pragma unroll
  for (int i = 0; i < 4; ++i) {
    int row = bm + ty * 4 + i;
    if (row >= M) continue;
    #pragma unroll
    for (int j = 0; j < 4; ++j) {
      int col = bn + tx * 4 + j;
      float v = acc[i][j];
      if (bias) v += bias[col];
      size_t off = (size_t)row * N + col;
      if (residual) C[off] += v; else C[off] = v;
    }
  }
}

// ---------------- bf16 MFMA GEMM (m97 structure): C = A(MxK) @ BT(NxK)^T + bias ----
// mode 0: Cb = result (bf16).  mode 1: Hf += result (fp32); Hb = bf16(new Hf).
// 128x128 tile, BK=32, 4 waves each 64x64. K=768. Unpadded LDS (64B rows) so
// global_load_lds lane-order matches; frag reads are contiguous-1KiB b128 patterns.
__global__ __launch_bounds__(256) void gemm_bf16(
    const unsigned short* __restrict__ A,
    const unsigned short* __restrict__ BT,
    const float* __restrict__ bias,
    unsigned short* __restrict__ Cb,
    float* __restrict__ Hf,
    unsigned short* __restrict__ Hb,
    int M, int N, int mode)
{
  constexpr int K = 768;
  __shared__ unsigned short As[128][32];
  __shared__ unsigned short Bs[128][32];
  int tid = threadIdx.x;
  int m0 = blockIdx.y * 128, n0 = blockIdx.x * 128;
  int w = tid >> 6, lane = tid & 63;
  int quad = lane >> 4, l16 = lane & 15;
  int wm = (w & 1) * 64, wn = (w >> 1) * 64;
  const int lrow = lane >> 2;          // 0..15 within an issue
  const int scol = (lane & 3) * 8;     // shorts
  float4v acc[4][4] = {};

  for (int k0 = 0; k0 < K; k0 += 32) {
    __syncthreads();
    #pragma unroll
    for (int e = 0; e < 2; ++e) {
      int r = w * 32 + e * 16;
      int ar = min(m0 + r + lrow, M - 1);
      gload_lds16(A + (size_t)ar * K + k0 + scol, &As[r][0]);
      gload_lds16(BT + (size_t)(n0 + r + lrow) * K + k0 + scol, &Bs[r][0]);
    }
    __syncthreads();
    short8 af[4], bfr[4];
    #pragma unroll
    for (int i = 0; i < 4; ++i) {
      af[i]  = *(const short8*)&As[wm + i * 16 + l16][quad * 8];
      bfr[i] = *(const short8*)&Bs[wn + i * 16 + l16][quad * 8];
    }
    #pragma unroll
    for (int i = 0; i < 4; ++i)
      #pragma unroll
      for (int j = 0; j < 4; ++j)
        acc[i][j] = __builtin_amdgcn_mfma_f32_16x16x32_bf16(af[i], bfr[j], acc[i][j], 0, 0, 0);
  }

  #pragma unroll
  for (int j = 0; j < 4; ++j) {
    int col = n0 + wn + j * 16 + l16;
    float bv = bias[col];
    #pragma unroll
    for (int i = 0; i < 4; ++i) {
      #pragma unroll
      for (int r = 0; r < 4; ++r) {
        int row = m0 + wm + i * 16 + quad * 4 + r;
        if (row < M) {
          float v = acc[i][j][r] + bv;
          size_t off = (size_t)row * N + col;
          if (mode == 0) {
            Cb[off] = f2bf(v);
          } else {
            float nv = Hf[off] + v;
            Hf[off] = nv;
            Hb[off] = f2bf(nv);
          }
        }
      }
    }
  }
}

// ---------------- spatial attention (bf16 MFMA, flash-tiled) ----------------
__global__ __launch_bounds__(256, 2) void attn_spatial3(
    const unsigned short* __restrict__ qkv,
    unsigned short* __restrict__ o)
{
  __shared__ unsigned short Qs[64][72];
  __shared__ unsigned short KVs[64][72];
  __shared__ unsigned short Ps[4][16][296];
  int tid = threadIdx.x;
  int w = tid >> 6, lane = tid & 63;
  int quad = lane >> 4, l16 = lane & 15;
  int bh = blockIdx.x, nt = bh / NH, head = bh % NH;
  size_t base = (size_t)nt * PTOT;
  const unsigned short* Qg = qkv + head * 64;
  const unsigned short* Kg = qkv + 768 + head * 64;
  const unsigned short* Vg = qkv + 1536 + head * 64;

  for (int q0 = 0; q0 < 320; q0 += 64) {
    __syncthreads();
    #pragma unroll
    for (int e = 0; e < 2; ++e) {
      int chunk = e * 256 + tid;
      int row = chunk >> 3, off = (chunk & 7) * 8;
      int qr = min(q0 + row, PTOT - 1);
      uint4 u = *(const uint4*)(Qg + (base + qr) * (size_t)QKVD + off);
      const unsigned short* pu = (const unsigned short*)&u;
      unsigned short s[8];
      #pragma unroll
      for (int i = 0; i < 8; ++i) {
        float f = bf2f(pu[i]) * 0.125f;
        unsigned ub; __builtin_memcpy(&ub, &f, 4);
        s[i] = (unsigned short)(ub >> 16);
      }
      *(uint4*)&Qs[row][off] = *(const uint4*)s;
    }
    __syncthreads();
    int qrow = w * 16 + l16;
    short8 qa0 = *(const short8*)&Qs[qrow][quad * 8];
    short8 qa1 = *(const short8*)&Qs[qrow][32 + quad * 8];

    float4v st[17];
    #pragma unroll
    for (int kc = 0; kc < 5; ++kc) {
      __syncthreads();
      #pragma unroll
      for (int e = 0; e < 2; ++e) {
        int chunk = e * 256 + tid;
        int row = chunk >> 3, off = (chunk & 7) * 8;
        int kr = min(kc * 64 + row, PTOT - 1);
        *(uint4*)&KVs[row][off] = *(const uint4*)(Kg + (base + kr) * (size_t)QKVD + off);
      }
      __syncthreads();
      #pragma unroll
      for (int tt = 0; tt < 4; ++tt) {
        int t = kc * 4 + tt;
        if (t < 17) {
          short8 kb0 = *(const short8*)&KVs[tt * 16 + l16][quad * 8];
          short8 kb1 = *(const short8*)&KVs[tt * 16 + l16][32 + quad * 8];
          float4v a = {0.f, 0.f, 0.f, 0.f};
          a = __builtin_amdgcn_mfma_f32_16x16x32_bf16(qa0, kb0, a, 0, 0, 0);
          a = __builtin_amdgcn_mfma_f32_16x16x32_bf16(qa1, kb1, a, 0, 0, 0);
          st[t] = a;
        }
      }
    }
    if (l16 >= 1) {
      st[16][0] = -1e30f; st[16][1] = -1e30f; st[16][2] = -1e30f; st[16][3] = -1e30f;
    }
    float mx[4] = {-1e30f, -1e30f, -1e30f, -1e30f};
    #pragma unroll
    for (int t = 0; t < 17; ++t)
      #pragma unroll
      for (int r = 0; r < 4; ++r) mx[r] = fmaxf(mx[r], st[t][r]);
    #pragma unroll
    for (int off = 1; off < 16; off <<= 1)
      #pragma unroll
      for (int r = 0; r < 4; ++r) mx[r] = fmaxf(mx[r], __shfl_xor(mx[r], off));
    float sm[4] = {0.f, 0.f, 0.f, 0.f};
    #pragma unroll
    for (int t = 0; t < 17; ++t)
      #pragma unroll
      for (int r = 0; r < 4; ++r) {
        float e = __expf(st[t][r] - mx[r]);
        st[t][r] = e;
        sm[r] += e;
      }
    #pragma unroll
    for (int off = 1; off < 16; off <<= 1)
      #pragma unroll
      for (int r = 0; r < 4; ++r) sm[r] += __shfl_xor(sm[r], off);
    float linv[4];
    #pragma unroll
    for (int r = 0; r < 4; ++r) linv[r] = 1.f / sm[r];

    #pragma unroll
    for (int t = 0; t < 17; ++t)
      #pragma unroll
      for (int r = 0; r < 4; ++r)
        Ps[w][quad * 4 + r][t * 16 + l16] = f2bf(st[t][r]);
    {
      ushort4 z = {0, 0, 0, 0};
      *(ushort4*)&Ps[w][lane >> 2][272 + (lane & 3) * 4] = z;
    }

    float4v oacc[4] = {};
    #pragma unroll
    for (int vc = 0; vc < 5; ++vc) {
      __syncthreads();
      #pragma unroll
      for (int e = 0; e < 2; ++e) {
        int chunk = e * 256 + tid;
        int row = chunk >> 3, off = (chunk & 7) * 8;
        int vr = min(vc * 64 + row, PTOT - 1);
        *(uint4*)&KVs[row][off] = *(const uint4*)(Vg + (base + vr) * (size_t)QKVD + off);
      }
      __syncthreads();
      int ksmax = (vc == 4) ? 1 : 2;
      for (int ks = 0; ks < ksmax; ++ks) {
        int kglob = vc * 64 + ks * 32;
        short8 pa = *(const short8*)&Ps[w][l16][kglob + quad * 8];
        #pragma unroll
        for (int j = 0; j < 4; ++j) {
          unsigned short vb[8];
          #pragma unroll
          for (int jj = 0; jj < 8; ++jj)
            vb[jj] = KVs[ks * 32 + quad * 8 + jj][j * 16 + l16];
          oacc[j] = __builtin_amdgcn_mfma_f32_16x16x32_bf16(pa, *(const short8*)vb, oacc[j], 0, 0, 0);
        }
      }
    }
    #pragma unroll
    for (int r = 0; r < 4; ++r) {
      int qg = q0 + w * 16 + quad * 4 + r;
      if (qg < PTOT) {
        #pragma unroll
        for (int j = 0; j < 4; ++j)
          o[(base + qg) * (size_t)D + head * 64 + j * 16 + l16] = f2bf(oacc[j][r] * linv[r]);
      }
    }
  }
}

// ---------------- temporal attention v2: one wave per (n,head,p), MFMA 16x16 ----
// grid = 6168/4 blocks, 4 waves/block, wave-private LDS, NO barriers.
__global__ __launch_bounds__(256) void attn_temporal2(const unsigned short* __restrict__ qkv,
                                                      unsigned short* __restrict__ o) {
  __shared__ unsigned short Ps[4][16][32];   // P padded to K=32 (cols 16..31 zero)
  __shared__ unsigned short VT[4][64][32];   // V^T padded to K=32
  int tid = threadIdx.x;
  int w = tid >> 6, lane = tid & 63;
  int quad = lane >> 4, l16 = lane & 15;
  int s = blockIdx.x * 4 + w;                // 0..6167
  int p  = s % PTOT;
  int nh = s / PTOT;
  int n = nh / NH, head = nh % NH;

  // zero k-padding (wave-local)
  {
    ushort4 z = {0, 0, 0, 0};
    *(ushort4*)&Ps[w][lane >> 2][16 + (lane & 3) * 4] = z;
    *(uint4*)&VT[w][lane][16] = (uint4){0, 0, 0, 0};
    *(uint4*)&VT[w][lane][24] = (uint4){0, 0, 0, 0};
  }

  const size_t rstride = (size_t)PTOT * QKVD;   // elements between consecutive t
  const unsigned short* base0 = qkv + ((size_t)(n * TT) * PTOT + p) * QKVD + head * 64;

  // Q/K fragments straight from global (row t = l16, 16B chunks)
  const unsigned short* qrow = base0 + (size_t)l16 * rstride;
  short8 qa0 = *(const short8*)(qrow + quad * 8);
  short8 qa1 = *(const short8*)(qrow + 32 + quad * 8);
  const unsigned short* krow = qrow + 768;
  short8 kb0 = *(const short8*)(krow + quad * 8);
  short8 kb1 = *(const short8*)(krow + 32 + quad * 8);

  float4v sc = {0.f, 0.f, 0.f, 0.f};
  sc = __builtin_amdgcn_mfma_f32_16x16x32_bf16(qa0, kb0, sc, 0, 0, 0);
  sc = __builtin_amdgcn_mfma_f32_16x16x32_bf16(qa1, kb1, sc, 0, 0, 0);

  // softmax across the 16 lanes of each quad (rows quad*4+r, cols l16)
  float e4[4], mx[4], sm[4];
  #pragma unroll
  for (int r = 0; r < 4; ++r) mx[r] = sc[r] * 0.125f;
  #pragma unroll
  for (int off = 1; off < 16; off <<= 1)
    #pragma unroll
    for (int r = 0; r < 4; ++r) mx[r] = fmaxf(mx[r], __shfl_xor(mx[r], off));
  #pragma unroll
  for (int r = 0; r < 4; ++r) { e4[r] = __expf(sc[r] * 0.125f - mx[r]); sm[r] = e4[r]; }
  #pragma unroll
  for (int off = 1; off < 16; off <<= 1)
    #pragma unroll
    for (int r = 0; r < 4; ++r) sm[r] += __shfl_xor(sm[r], off);
  float linv[4];
  #pragma unroll
  for (int r = 0; r < 4; ++r) linv[r] = 1.f / sm[r];

  // P -> LDS (A-layout source)
  #pragma unroll
  for (int r = 0; r < 4; ++r) Ps[w][quad * 4 + r][l16] = f2bf(e4[r]);

  // V^T -> LDS: lane covers V row t'=l16, dims quad*16..quad*16+15
  {
    const unsigned short* vrow = qrow + 1536 + quad * 16;
    uint4 v0 = *(const uint4*)vrow;
    uint4 v1 = *(const uint4*)(vrow + 8);
    const unsigned short* pv0 = (const unsigned short*)&v0;
    const unsigned short* pv1 = (const unsigned short*)&v1;
    #pragma unroll
    for (int i = 0; i < 8; ++i) VT[w][quad * 16 + i][l16]     = pv0[i];
    #pragma unroll
    for (int i = 0; i < 8; ++i) VT[w][quad * 16 + 8 + i][l16] = pv1[i];
  }

  // PV: O[16 q][64 d] = P @ V, 4 MFMAs over d-tiles
  short8 pa = *(const short8*)&Ps[w][l16][quad * 8];
  float4v oacc[4];
  #pragma unroll
  for (int j = 0; j < 4; ++j) {
    short8 vb = *(const short8*)&VT[w][j * 16 + l16][quad * 8];
    float4v z = {0.f, 0.f, 0.f, 0.f};
    oacc[j] = __builtin_amdgcn_mfma_f32_16x16x32_bf16(pa, vb, z, 0, 0, 0);
  }

  // store: row t = quad*4+r, col head*64 + j*16 + l16
  #pragma unroll
  for (int r = 0; r < 4; ++r) {
    size_t orow = ((size_t)(n * TT + quad * 4 + r) * PTOT + p) * D + head * 64;
    #pragma unroll
    for (int j = 0; j < 4; ++j)
      o[orow + j * 16 + l16] = f2bf(oacc[j][r] * linv[r]);
  }
}

// ---------------- final LN on cls rows + mean over t + head ----------------
__device__ __forceinline__ float block_sum(float v, float* lds) {
  #pragma unroll
  for (int off = 32; off; off >>= 1) v += __shfl_down(v, off);
  __syncthreads();
  if ((threadIdx.x & 63) == 0) lds[threadIdx.x >> 6] = v;
  __syncthreads();
  return lds[0] + lds[1] + lds[2] + lds[3];
}

__global__ __launch_bounds__(256) void head_kernel(const float* __restrict__ h,
    const float* __restrict__ g, const float* __restrict__ b,
    const float* __restrict__ hw, const float* __restrict__ hb,
    float* __restrict__ out) {
  __shared__ float lds[4];
  int n = blockIdx.x, tid = threadIdx.x;
  float logit = 0.f;
  for (int t = 0; t < TT; ++t) {
    const float* row = h + (size_t)((n * TT + t) * PTOT) * D;
    float v[3]; float s = 0.f;
    #pragma unroll
    for (int i = 0; i < 3; ++i) { v[i] = row[tid + 256 * i]; s += v[i]; }
    s = block_sum(s, lds);
    float mu = s * (1.f / D);
    float s2 = 0.f;
    #pragma unroll
    for (int i = 0; i < 3; ++i) { float d0 = v[i] - mu; s2 += d0 * d0; }
    s2 = block_sum(s2, lds);
    float rstd = rsqrtf(s2 * (1.f / D) + 1e-5f);
    float dot = 0.f;
    #pragma unroll
    for (int i = 0; i < 3; ++i) {
      int d0 = tid + 256 * i;
      float y = (v[i] - mu) * rstd * g[d0] + b[d0];
      dot += y * hw[d0];
    }
    dot = block_sum(dot, lds);
    logit += dot;
  }
  if (tid == 0) out[n] = logit * (1.f / TT) + hb[0];
}

} // namespace

extern "C" void kernel_launch(void* const* d_in, const int* in_sizes, int n_in,
                              void* d_out, int out_size, void* d_ws, size_t ws_size,
                              hipStream_t stream) {
  const float* x       = (const float*)d_in[0];
  const float* patch_w = (const float*)d_in[1];
  const float* patch_b = (const float*)d_in[2];
  const float* cls     = (const float*)d_in[3];
  const float* pos     = (const float*)d_in[4];
  const float* tim     = (const float*)d_in[5];
  const float* wqkv_s  = (const float*)d_in[6];
  const float* bqkv_s  = (const float*)d_in[7];
  const float* wqkv_t  = (const float*)d_in[8];
  const float* bqkv_t  = (const float*)d_in[9];
  const float* wproj   = (const float*)d_in[10];
  const float* bproj   = (const float*)d_in[11];
  const float* ln_g    = (const float*)d_in[12];
  const float* ln_b    = (const float*)d_in[13];
  const float* head_w  = (const float*)d_in[14];
  const float* head_b  = (const float*)d_in[15];
  float* out = (float*)d_out;

  // ---- workspace layout ----
  char* p = (char*)d_ws;
  float* h = (float*)p;                 p += (size_t)NTOK * D * 4;
  unsigned short* hb = (unsigned short*)p;   p += (size_t)NTOK * D * 2;
  unsigned short* qkvb = (unsigned short*)p; p += (size_t)NTOK * QKVD * 2;
  unsigned short* ob = (unsigned short*)p;   p += (size_t)NTOK * D * 2;
  unsigned short* wsT = (unsigned short*)p;  p += (size_t)12 * QKVD * D * 2;
  unsigned short* wtT = (unsigned short*)p;  p += (size_t)12 * QKVD * D * 2;
  unsigned short* wpT = (unsigned short*)p;  p += (size_t)12 * D * D * 2;
  float* xp  = (float*)qkvb;
  float* pwT = (float*)ob;
  float* tok = (float*)wsT;

  // ---- patch embed (fp32 for accuracy) ----
  unfold_kernel<<<(NPAT * D + 255) / 256, 256, 0, stream>>>(x, xp);
  transpose_pw<<<(D * D + 255) / 256, 256, 0, stream>>>(patch_w, pwT);
  gemm_nn<<<dim3(D / 64, NPAT / 64), 256, 0, stream>>>(xp, pwT, nullptr, tok, NPAT, D, D, 0);
  assemble_kernel<<<(NTOK * D + 255) / 256, 256, 0, stream>>>(tok, patch_b, cls, pos, tim, h, hb);

  // ---- weights -> transposed bf16 ----
  wconv<<<dim3(QKVD / 32, D / 32, 12), 256, 0, stream>>>(wqkv_s, wsT, QKVD);
  wconv<<<dim3(QKVD / 32, D / 32, 12), 256, 0, stream>>>(wqkv_t, wtT, QKVD);
  wconv<<<dim3(D / 32, D / 32, 12), 256, 0, stream>>>(wproj, wpT, D);

  // ---- transformer layers ----
  const int MB = (NTOK + 127) / 128;   // 65
  for (int l = 0; l < 12; ++l) {
    gemm_bf16<<<dim3(QKVD / 128, MB), 256, 0, stream>>>(
        hb, wsT + (size_t)l * QKVD * D, bqkv_s + (size_t)l * QKVD,
        qkvb, nullptr, nullptr, NTOK, QKVD, 0);
    attn_spatial3<<<NB * TT * NH, 256, 0, stream>>>(qkvb, ob);
    gemm_bf16<<<dim3(D / 128, MB), 256, 0, stream>>>(
        ob, wpT + (size_t)l * D * D, bproj + (size_t)l * D,
        nullptr, h, hb, NTOK, D, 1);

    gemm_bf16<<<dim3(QKVD / 128, MB), 256, 0, stream>>>(
        hb, wtT + (size_t)l * QKVD * D, bqkv_t + (size_t)l * QKVD,
        qkvb, nullptr, nullptr, NTOK, QKVD, 0);
    attn_temporal2<<<(NB * NH * PTOT) / 4, 256, 0, stream>>>(qkvb, ob);
    gemm_bf16<<<dim3(D / 128, MB), 256, 0, stream>>>(
        ob, wpT + (size_t)l * D * D, bproj + (size_t)l * D,
        nullptr, h, hb, NTOK, D, 1);
  }

  // ---- final LN (cls rows only) + temporal mean + head ----
  head_kernel<<<2, 256, 0, stream>>>(h, ln_g, ln_b, head_w, head_b, out);
}